// Round 13
// baseline (188.102 us; speedup 1.0000x reference)
//
#include <hip/hip_runtime.h>
#include <hip/hip_fp16.h>

#define B_SZ 4096
#define T_SZ 200
#define IN_SZ 34
#define GSEQ 8                      // sequences per workgroup
#define NWG (B_SZ / GSEQ)           // 512 workgroups
#define ROWS (GSEQ * T_SZ)          // 1600 rows per workgroup
#define LDS_T_STRIDE 33             // uint2 per t (32 used + 1 pad)
// HIDDEN = 4, 4*H = 16 gates, gate order i,f,g,o (rows of W_ih/W_hh)
//
// Fully fused: each workgroup (256 thr) owns 8 sequences.
//  Phase A: gates fp16 -> LDS [t][s*4+q] (stride 33 uint2). 4 lanes per row
//           split k; weights preloaded per-lane into VGPRs; quad-DPP reduce.
//  Phase B: scan from LDS, 2 seqs per wave, R5-proven step numerics.

__device__ __forceinline__ float sigf(float x) {
    return 1.0f / (1.0f + __expf(-x));
}
__device__ __forceinline__ float tanh_f(float x) {
    return 2.0f / (1.0f + __expf(-2.0f * x)) - 1.0f;
}

// quad broadcasts (lane L of each 4-lane group to all 4)
__device__ __forceinline__ float quad_bcast0(float v) {
    int s = __float_as_int(v);
    return __int_as_float(__builtin_amdgcn_update_dpp(s, s, 0x00, 0xf, 0xf, true));
}
__device__ __forceinline__ float quad_bcast1(float v) {
    int s = __float_as_int(v);
    return __int_as_float(__builtin_amdgcn_update_dpp(s, s, 0x55, 0xf, 0xf, true));
}
__device__ __forceinline__ float quad_bcast2(float v) {
    int s = __float_as_int(v);
    return __int_as_float(__builtin_amdgcn_update_dpp(s, s, 0xAA, 0xf, 0xf, true));
}
__device__ __forceinline__ float quad_bcast3(float v) {
    int s = __float_as_int(v);
    return __int_as_float(__builtin_amdgcn_update_dpp(s, s, 0xFF, 0xf, 0xf, true));
}
// quad butterfly all-reduce (sum over the 4 lanes of each quad)
__device__ __forceinline__ float quad_red(float v) {
    int s = __float_as_int(v);
    v += __int_as_float(__builtin_amdgcn_update_dpp(s, s, 0xB1, 0xf, 0xf, true)); // [1,0,3,2]
    s = __float_as_int(v);
    v += __int_as_float(__builtin_amdgcn_update_dpp(s, s, 0x4E, 0xf, 0xf, true)); // [2,3,0,1]
    return v;
}
__device__ __forceinline__ float qsel(float a0, float a1, float a2, float a3, int q) {
    return q == 0 ? a0 : q == 1 ? a1 : q == 2 ? a2 : a3;
}

__global__ __launch_bounds__(256, 2) void lstm_all(
    const float* __restrict__ x, const float* __restrict__ W_ih,
    const float* __restrict__ W_hh, const float* __restrict__ b_ih,
    const float* __restrict__ b_hh, const float* __restrict__ W_fc,
    const float* __restrict__ b_fc, float* __restrict__ out) {
  __shared__ uint2 gl[T_SZ * LDS_T_STRIDE];  // 52,800 B
  const int tid = threadIdx.x;
  const int q = tid & 3;            // gate-column / k-split lane
  const int rowslot = tid >> 2;     // 0..63
  const int wg = blockIdx.x;

  // ---- per-lane weight preload (stays in VGPRs; all static indexing) ----
  // lane q's k-set: k = 2q + 8*(m>>1) + (m&1) for m=0..7 (covers 0..31);
  // tail k=32 -> q0, k=33 -> q1 (slot 8; zeroed otherwise).
  float wk[9][16];
  #pragma unroll
  for (int m = 0; m < 8; ++m) {
    int k = 2 * q + ((m >> 1) << 3) + (m & 1);
    #pragma unroll
    for (int g = 0; g < 16; ++g) wk[m][g] = W_ih[g * IN_SZ + k];
  }
  #pragma unroll
  for (int g = 0; g < 16; ++g)
    wk[8][g] = (q < 2) ? W_ih[g * IN_SZ + 32 + q] : 0.f;
  float bias4[4];  // lane q's gates: i=q, f=4+q, g=8+q, o=12+q
  #pragma unroll
  for (int z = 0; z < 4; ++z) bias4[z] = b_ih[z * 4 + q] + b_hh[z * 4 + q];

  // ---- Phase A: gates for this wg's 1600 rows -> LDS ----
  const float* xbase = x + (size_t)wg * (ROWS * IN_SZ);
  #pragma unroll 1
  for (int i = 0; i < ROWS / 64; ++i) {        // 25 iterations
    int ri = rowslot + 64 * i;                  // 0..1599
    const char* rp = reinterpret_cast<const char*>(xbase + (size_t)ri * IN_SZ);
    float xv[9];
    #pragma unroll
    for (int m2 = 0; m2 < 4; ++m2) {            // quad-coalesced 32B chunks
      float2 v = *reinterpret_cast<const float2*>(rp + q * 8 + m2 * 32);
      xv[2 * m2] = v.x;
      xv[2 * m2 + 1] = v.y;
    }
    xv[8] = (q < 2) ? *reinterpret_cast<const float*>(rp + 128 + q * 4) : 0.f;

    float acc[16];
    #pragma unroll
    for (int g = 0; g < 16; ++g) acc[g] = 0.f;
    #pragma unroll
    for (int m = 0; m < 9; ++m) {
      #pragma unroll
      for (int g = 0; g < 16; ++g) acc[g] = fmaf(xv[m], wk[m][g], acc[g]);
    }
    // sum partials across the quad (every lane gets full sums)
    #pragma unroll
    for (int g = 0; g < 16; ++g) acc[g] = quad_red(acc[g]);
    // lane q keeps its gate column
    float vi = qsel(acc[0], acc[1], acc[2], acc[3], q) + bias4[0];
    float vf = qsel(acc[4], acc[5], acc[6], acc[7], q) + bias4[1];
    float vg = qsel(acc[8], acc[9], acc[10], acc[11], q) + bias4[2];
    float vo = qsel(acc[12], acc[13], acc[14], acc[15], q) + bias4[3];
    unsigned s = (unsigned)ri / 200u;
    unsigned t = (unsigned)ri - s * 200u;
    union { __half2 h[2]; uint2 v; } u;
    u.h[0] = __floats2half2_rn(vi, vf);
    u.h[1] = __floats2half2_rn(vg, vo);
    gl[t * LDS_T_STRIDE + s * 4 + q] = u.v;
  }
  __syncthreads();

  // ---- Phase B: scan. wave w handles seqs 2w, 2w+1 on lanes 0..7 ----
  const int l = tid & 63;
  const int w = tid >> 6;
  if (l < 8) {
    const int s = 2 * w + (l >> 2);
    const int jq = l & 3;
    float Wi[4], Wf[4], Wg[4], Wo[4];
    #pragma unroll
    for (int k = 0; k < 4; ++k) {
      Wi[k] = W_hh[(0 + jq) * 4 + k];
      Wf[k] = W_hh[(4 + jq) * 4 + k];
      Wg[k] = W_hh[(8 + jq) * 4 + k];
      Wo[k] = W_hh[(12 + jq) * 4 + k];
    }
    float h[4] = {0.f, 0.f, 0.f, 0.f};
    float c = 0.f;

    auto step = [&](uint2 wv) {
      union { uint2 u; __half2 h2[2]; } v;
      v.u = wv;
      float2 p01 = __half22float2(v.h2[0]);  // (i, f)
      float2 p23 = __half22float2(v.h2[1]);  // (g, o)
      float pi = p01.x, pf = p01.y, pg = p23.x, po = p23.y;
      #pragma unroll
      for (int k = 0; k < 4; ++k) {
        pi = fmaf(Wi[k], h[k], pi);
        pf = fmaf(Wf[k], h[k], pf);
        pg = fmaf(Wg[k], h[k], pg);
        po = fmaf(Wo[k], h[k], po);
      }
      float iv = sigf(pi);
      float fv = sigf(pf);
      float gv = tanh_f(pg);
      float ov = sigf(po);
      c = fmaf(fv, c, iv * gv);
      float hj = ov * tanh_f(c);
      h[0] = quad_bcast0(hj);
      h[1] = quad_bcast1(hj);
      h[2] = quad_bcast2(hj);
      h[3] = quad_bcast3(hj);
    };

    const uint2* lp = &gl[s * 4 + jq];
    #pragma unroll 1
    for (int tb = 0; tb < 20; ++tb) {
      uint2 v[10];
      #pragma unroll
      for (int u = 0; u < 10; ++u)
        v[u] = lp[(size_t)(tb * 10 + u) * LDS_T_STRIDE];  // batch ds_reads
      #pragma unroll
      for (int u = 0; u < 10; ++u) step(v[u]);
    }

    if (jq < 3) {
      float a = b_fc[jq];
      #pragma unroll
      for (int k = 0; k < 4; ++k) a = fmaf(W_fc[jq * 4 + k], h[k], a);
      out[(wg * GSEQ + s) * 3 + jq] = a;
    }
  }
}

extern "C" void kernel_launch(void* const* d_in, const int* in_sizes, int n_in,
                              void* d_out, int out_size, void* d_ws, size_t ws_size,
                              hipStream_t stream) {
  const float* x    = (const float*)d_in[0];
  const float* W_ih = (const float*)d_in[1];
  const float* W_hh = (const float*)d_in[2];
  const float* b_ih = (const float*)d_in[3];
  const float* b_hh = (const float*)d_in[4];
  const float* W_fc = (const float*)d_in[5];
  const float* b_fc = (const float*)d_in[6];
  float* out = (float*)d_out;
  (void)in_sizes; (void)n_in; (void)out_size; (void)d_ws; (void)ws_size;

  hipLaunchKernelGGL(lstm_all, dim3(NWG), dim3(256), 0, stream,
                     x, W_ih, W_hh, b_ih, b_hh, W_fc, b_fc, out);
}